// Round 3
// baseline (395.670 us; speedup 1.0000x reference)
//
#include <hip/hip_runtime.h>
#include <math.h>

#define T_DIM 8192
#define D_DIM 7168
#define E_DIM 256
#define N_GROUPS 8
#define TOPK_GROUPS 4
#define TOP_K 8

#define N_TOK 128     // tokens per GEMM block (halves W^T refetch traffic)
#define BK 32         // k per chunk (one 16x16x32 MFMA k-step)
#define CHUNK_HALVES (E_DIM * BK)     // 8192 halves = 16 KB image per chunk per hi/lo
#define WSCALE 512.0f
#define INV_WSCALE (1.0f / 512.0f)

typedef _Float16 half8 __attribute__((ext_vector_type(8)));
typedef _Float16 half4v __attribute__((ext_vector_type(4)));
typedef float floatx4 __attribute__((ext_vector_type(4)));

// global->LDS async DMA, 16B per lane. LDS dest is wave-uniform base
// (HW appends lane*16); global source is per-lane.
#define GLOAD_LDS16(gp, lp)                                                     \
    __builtin_amdgcn_global_load_lds(                                           \
        (const __attribute__((address_space(1))) void*)(gp),                    \
        (__attribute__((address_space(3))) void*)(lp), 16, 0, 0)

#define WAITV(n) asm volatile("s_waitcnt vmcnt(" #n ")" ::: "memory")
#define WAITLGKM asm volatile("s_waitcnt lgkmcnt(0)" ::: "memory")
#define SCHEDB __builtin_amdgcn_sched_barrier(0)

// ---------------------------------------------------------------------------
// Kernel 0: split W [D][E] fp32 -> wph/wpl, stored as per-chunk GEMM-ready
// swizzled LDS images (BK=32): chunk c holds the halves for k in
// [c*32, c*32+32); the half for (expert e, k = c*32 + g*8 + j) lives at
// halves-offset  e*32 + ((g ^ ((e>>1)&3))<<3) + j  within the chunk.
// Linear DMA dest + pre-swizzled source (rule #21); swizzle keeps the GEMM's
// ds_read_b128 fragments at the free 2-way/quarter-wave aliasing floor.
// ---------------------------------------------------------------------------
__global__ __launch_bounds__(256) void wprep_kernel(
    const float* __restrict__ w, _Float16* __restrict__ wph, _Float16* __restrict__ wpl)
{
    __shared__ float tile[64][65];
    const int k0 = blockIdx.x * 64, e0 = blockIdx.y * 64;
    const int tid = threadIdx.x;
    {
        const int kk = tid >> 4, e4 = (tid & 15) * 4;
#pragma unroll
        for (int i = 0; i < 4; i++) {
            const float4 v = *(const float4*)(w + (size_t)(k0 + kk + i * 16) * E_DIM + e0 + e4);
            tile[kk + i * 16][e4 + 0] = v.x;
            tile[kk + i * 16][e4 + 1] = v.y;
            tile[kk + i * 16][e4 + 2] = v.z;
            tile[kk + i * 16][e4 + 3] = v.w;
        }
    }
    __syncthreads();
    {
        const int ee = tid >> 4, kk4 = (tid & 15) * 4;
        const int c_in = (k0 + kk4) >> 5;       // global chunk index
        const int g = (kk4 >> 3) & 3;           // granule within chunk
        const int j0 = kk4 & 7;                 // offset within granule (0 or 4)
#pragma unroll
        for (int i = 0; i < 4; i++) {
            const int el = ee + i * 16;
            const int e = e0 + el;
            half4v hh, ll;
#pragma unroll
            for (int j = 0; j < 4; j++) {
                const float v = tile[kk4 + j][el] * WSCALE;
                const _Float16 h = (_Float16)v;
                hh[j] = h;
                ll[j] = (_Float16)(v - (float)h);
            }
            const size_t off = (size_t)c_in * CHUNK_HALVES + (size_t)e * BK +
                               (((g ^ ((e >> 1) & 3)) << 3) + j0);
            *(half4v*)(wph + off) = hh;
            *(half4v*)(wpl + off) = ll;
        }
    }
}

// ---------------------------------------------------------------------------
// Kernel 1: split-fp16 MFMA GEMM, N_TOK=128, 512 threads (8 waves =
// 4 expert-groups x 2 token-groups). A triple-buffered, DMA'd 2 chunks
// ahead; x loaded to regs 2 ahead; B double-buffered. Raw s_barrier with
// counted vmcnt (T4): steady state 12 outstanding vmem = {x2,A4} x 2 chunks;
// WAITV(10) retires {A(i), x(i+1)}, WAITV(6) retires A(i+1) before the
// barrier that publishes chunk i+1. Never drains to 0 in the main loop.
// ---------------------------------------------------------------------------
__device__ __forceinline__ void cvt_split8(const float4 v0, const float4 v1,
                                           half8& h, half8& l)
{
    float f[8] = {v0.x, v0.y, v0.z, v0.w, v1.x, v1.y, v1.z, v1.w};
#pragma unroll
    for (int j = 0; j < 8; j++) {
        const _Float16 hh = (_Float16)f[j];
        h[j] = hh;
        l[j] = (_Float16)(f[j] - (float)hh);
    }
}

// Each of 8 waves stages 2 KB of hi + 2 KB of lo (4 DMAs).
#define STAGE_A_DMA(c, buf)                                                   \
    do {                                                                      \
        const size_t cb_ = (size_t)(c) * CHUNK_HALVES;                        \
        const char* gh_ = (const char*)(wph + cb_) + wave * 2048 + lane * 16; \
        const char* gl_ = (const char*)(wpl + cb_) + wave * 2048 + lane * 16; \
        char* lh_ = (char*)&As[buf][0][0] + wave * 2048;                      \
        char* ll_ = (char*)&As[buf][1][0] + wave * 2048;                      \
        GLOAD_LDS16(gh_, lh_);                                                \
        GLOAD_LDS16(gh_ + 1024, lh_ + 1024);                                  \
        GLOAD_LDS16(gl_, ll_);                                                \
        GLOAD_LDS16(gl_ + 1024, ll_ + 1024);                                  \
    } while (0)

#define STAGE_A_CONV(kc_, buf)                                                \
    do {                                                                      \
        _Pragma("unroll")                                                     \
        for (int i_ = 0; i_ < 4; i_++) {                                      \
            const int f_ = tid + i_ * 512;                                    \
            const int kk_ = f_ >> 6;                                          \
            const int e4_ = (f_ & 63) << 2;                                   \
            const float4 v_ = *(const float4*)(wraw + (size_t)((kc_) + kk_) * E_DIM + e4_); \
            const float fv_[4] = {v_.x, v_.y, v_.z, v_.w};                    \
            const int g_ = (kk_ >> 3) & 3, ko_ = kk_ & 7;                     \
            _Pragma("unroll")                                                 \
            for (int j_ = 0; j_ < 4; j_++) {                                  \
                const int e_ = e4_ + j_;                                      \
                const float sv_ = fv_[j_] * WSCALE;                           \
                const _Float16 hh_ = (_Float16)sv_;                           \
                const int off_ = e_ * BK + ((g_ ^ ((e_ >> 1) & 3)) << 3) + ko_; \
                As[buf][0][off_] = hh_;                                       \
                As[buf][1][off_] = (_Float16)(sv_ - (float)hh_);              \
            }                                                                 \
        }                                                                     \
    } while (0)

#define WRITE_B(buf, h_, l_)                                                  \
    do {                                                                      \
        const int boff_ = bt * BK + ((bg ^ ((bt >> 1) & 3)) << 3);            \
        *(half8*)&Bs[buf][0][boff_] = (h_);                                   \
        *(half8*)&Bs[buf][1][boff_] = (l_);                                   \
    } while (0)

#define COMPUTE_CHUNK(ab, bb)                                                 \
    do {                                                                      \
        half8 ah[4], al[4];                                                   \
        _Pragma("unroll")                                                     \
        for (int mt = 0; mt < 4; mt++) {                                      \
            const int e_ = we0 + mt * 16 + lm;                                \
            const int off_ = e_ * BK + ((kq ^ ((e_ >> 1) & 3)) << 3);         \
            ah[mt] = *(const half8*)&As[ab][0][off_];                         \
            al[mt] = *(const half8*)&As[ab][1][off_];                         \
        }                                                                     \
        __builtin_amdgcn_s_setprio(1);                                        \
        _Pragma("unroll")                                                     \
        for (int nt = 0; nt < 4; nt++) {                                      \
            const int t_ = tg * 64 + nt * 16 + lm;                            \
            const int off_ = t_ * BK + ((kq ^ ((t_ >> 1) & 3)) << 3);         \
            const half8 bh = *(const half8*)&Bs[bb][0][off_];                 \
            const half8 bl = *(const half8*)&Bs[bb][1][off_];                 \
            _Pragma("unroll")                                                 \
            for (int mt = 0; mt < 4; mt++) {                                  \
                acc[mt][nt] = __builtin_amdgcn_mfma_f32_16x16x32_f16(ah[mt], bh, acc[mt][nt], 0, 0, 0); \
                acc[mt][nt] = __builtin_amdgcn_mfma_f32_16x16x32_f16(ah[mt], bl, acc[mt][nt], 0, 0, 0); \
                acc[mt][nt] = __builtin_amdgcn_mfma_f32_16x16x32_f16(al[mt], bh, acc[mt][nt], 0, 0, 0); \
            }                                                                 \
        }                                                                     \
        __builtin_amdgcn_s_setprio(0);                                        \
    } while (0)

template <bool CONVW>
__global__ __launch_bounds__(512, 2) void gemm_split_kernel(
    const float* __restrict__ x, const _Float16* __restrict__ wph,
    const _Float16* __restrict__ wpl, const float* __restrict__ wraw,
    float* __restrict__ partial, int kslen)
{
    __shared__ _Float16 As[3][2][CHUNK_HALVES];   // 3-buf x {hi,lo} = 96 KB
    __shared__ _Float16 Bs[2][2][N_TOK * BK];     // 2-buf x {hi,lo} = 32 KB

    const int s = blockIdx.x, m = blockIdx.y;
    const int tid = threadIdx.x;
    const int k0 = s * kslen;
    const size_t t0 = (size_t)m * N_TOK;

    const int wave = tid >> 6, lane = tid & 63;
    const int lm = lane & 15, kq = lane >> 4;  // fragment row / k-granule
    const int we0 = (wave & 3) * 64;           // wave's expert base
    const int tg = wave >> 2;                  // wave's token half (0/1)

    // B staging map: thread -> (token, k-granule)
    const int bt = tid >> 2;   // 0..127
    const int bg = tid & 3;    // 0..3
    const float* xrow = x + (t0 + bt) * (size_t)D_DIM + bg * 8;

    floatx4 acc[4][4];
#pragma unroll
    for (int mt = 0; mt < 4; mt++)
#pragma unroll
        for (int nt = 0; nt < 4; nt++) acc[mt][nt] = (floatx4)0.0f;

    const int nch = kslen / BK;   // 56 at KS=4
    const int cbase = k0 / BK;

    if (CONVW) {
        // simple synchronous fallback (used only if workspace is tiny)
        for (int i = 0; i < nch; ++i) {
            const int kc = k0 + i * BK;
            STAGE_A_CONV(kc, 0);
            const float4 a0 = *(const float4*)(xrow + kc);
            const float4 a1 = *(const float4*)(xrow + kc + 4);
            half8 h, l;
            cvt_split8(a0, a1, h, l);
            WRITE_B(0, h, l);
            __syncthreads();
            COMPUTE_CHUNK(0, 0);
            __syncthreads();
        }
    } else {
        // ---- prologue: x0,A0,x1,A1 issued; B0 written; A0 landed ----
        const float4 p0 = *(const float4*)(xrow + k0);
        const float4 p1 = *(const float4*)(xrow + k0 + 4);
        SCHEDB;
        STAGE_A_DMA(cbase + 0, 0);
        SCHEDB;
        float4 c0 = *(const float4*)(xrow + k0 + BK);
        float4 c1 = *(const float4*)(xrow + k0 + BK + 4);
        SCHEDB;
        STAGE_A_DMA(cbase + 1, 1);
        SCHEDB;
        WAITV(10);                 // retire x0 (leaves A0 x1 A1 = 10)
        SCHEDB;
        {
            half8 h, l;
            cvt_split8(p0, p1, h, l);
            WRITE_B(0, h, l);
        }
        WAITV(6);                  // retire A0 (leaves x1 A1 = 6)
        WAITLGKM;
        SCHEDB;
        __builtin_amdgcn_s_barrier();
        SCHEDB;

        // ---- main loop: compute i, DMA i+2, write B(i+1) ----
        int bufC = 0, bufS = 2, bW = 1, bR = 0;
        for (int i = 0; i < nch - 2; ++i) {
            const int kn = k0 + (i + 2) * BK;
            const float4 n0 = *(const float4*)(xrow + kn);
            const float4 n1 = *(const float4*)(xrow + kn + 4);
            SCHEDB;
            STAGE_A_DMA(cbase + i + 2, bufS);
            SCHEDB;

            COMPUTE_CHUNK(bufC, bR);

            WAITV(10);             // retire A(i) + x(i+1): c regs valid
            SCHEDB;
            {
                half8 h, l;
                cvt_split8(c0, c1, h, l);
                WRITE_B(bW, h, l);
            }
            c0 = n0; c1 = n1;
            WAITV(6);              // retire A(i+1): next tile landed
            WAITLGKM;              // B(i+1) writes done
            SCHEDB;
            __builtin_amdgcn_s_barrier();
            SCHEDB;

            bufC = (bufC == 2) ? 0 : bufC + 1;
            bufS = (bufS == 2) ? 0 : bufS + 1;
            bW ^= 1; bR ^= 1;
        }

        // ---- chunk nch-2: no new issues ----
        COMPUTE_CHUNK(bufC, bR);
        WAITV(4);                  // retire x(nch-1)
        SCHEDB;
        {
            half8 h, l;
            cvt_split8(c0, c1, h, l);
            WRITE_B(bW, h, l);
        }
        WAITV(0);                  // A(nch-1) landed
        WAITLGKM;
        SCHEDB;
        __builtin_amdgcn_s_barrier();
        SCHEDB;
        bufC = (bufC == 2) ? 0 : bufC + 1;
        bR ^= 1;

        // ---- chunk nch-1 ----
        COMPUTE_CHUNK(bufC, bR);
    }

    // ---- epilogue: store raw z' partials. C/D: col(token)=lane&15, row(e)=(lane>>4)*4+r
    float* pout = partial + (size_t)s * T_DIM * E_DIM;
    const int rq = lane >> 4;
#pragma unroll
    for (int nt = 0; nt < 4; nt++) {
        const size_t t = t0 + tg * 64 + nt * 16 + lm;
#pragma unroll
        for (int mt = 0; mt < 4; mt++) {
            const int e = we0 + mt * 16 + rq * 4;
            *(floatx4*)(pout + t * E_DIM + e) = acc[mt][nt];
        }
    }
}

// ---------------------------------------------------------------------------
// Kernel 2: per-token routing. One wave per token, no barriers.
// Sums KS partials, z = sum * (1/512), score = sigmoid(z).
// ---------------------------------------------------------------------------
__global__ __launch_bounds__(64) void router_kernel(
    const float* __restrict__ partial, const float* __restrict__ bias,
    float* __restrict__ w_out, float* __restrict__ i_out, int ks)
{
    const int t = blockIdx.x;
    const int lane = threadIdx.x;

    __shared__ float sraw[E_DIM];

    float4 zv = make_float4(0.f, 0.f, 0.f, 0.f);
    for (int s = 0; s < ks; s++) {
        const float4 p = *(const float4*)(partial + (size_t)s * T_DIM * E_DIM +
                                          (size_t)t * E_DIM + lane * 4);
        zv.x += p.x; zv.y += p.y; zv.z += p.z; zv.w += p.w;
    }
    float4 sv;
    sv.x = 1.0f / (1.0f + expf(-zv.x * INV_WSCALE));
    sv.y = 1.0f / (1.0f + expf(-zv.y * INV_WSCALE));
    sv.z = 1.0f / (1.0f + expf(-zv.z * INV_WSCALE));
    sv.w = 1.0f / (1.0f + expf(-zv.w * INV_WSCALE));

    const float4 bz = *(const float4*)(bias + lane * 4);
    *(float4*)(&sraw[lane * 4]) = sv; // single wave: no barrier needed

    float sb[4];
    sb[0] = sv.x + bz.x; sb[1] = sv.y + bz.y; sb[2] = sv.z + bz.z; sb[3] = sv.w + bz.w;

    // group top-2 sum (8 lanes per group)
    float m1 = -INFINITY, m2 = -INFINITY;
#pragma unroll
    for (int j = 0; j < 4; j++) {
        const float v = sb[j];
        if (v > m1) { m2 = m1; m1 = v; }
        else if (v > m2) { m2 = v; }
    }
#pragma unroll
    for (int d = 1; d < 8; d <<= 1) {
        const float o1 = __shfl_xor(m1, d);
        const float o2 = __shfl_xor(m2, d);
        const float hi = fmaxf(m1, o1);
        const float lo = fminf(m1, o1);
        m2 = fmaxf(lo, fmaxf(m2, o2));
        m1 = hi;
    }
    const float gscore = m1 + m2;

    float gs[N_GROUPS];
#pragma unroll
    for (int g = 0; g < N_GROUPS; g++) gs[g] = __shfl(gscore, g * 8);

    unsigned gmask = 0u;
#pragma unroll
    for (int r = 0; r < TOPK_GROUPS; r++) {
        int best = 0; float bv = -INFINITY;
#pragma unroll
        for (int g = 0; g < N_GROUPS; g++) {
            const bool taken = (gmask >> g) & 1u;
            if (!taken && gs[g] > bv) { bv = gs[g]; best = g; }
        }
        gmask |= (1u << best);
    }

    const int myg = lane >> 3;
    const float keep = ((gmask >> myg) & 1u) ? 1.0f : 0.0f;
    float v[4];
#pragma unroll
    for (int j = 0; j < 4; j++) v[j] = keep * sb[j];

    int selIdx[TOP_K];
#pragma unroll
    for (int it = 0; it < TOP_K; it++) {
        float bv = -INFINITY; int bi = E_DIM;
#pragma unroll
        for (int j = 0; j < 4; j++) {
            if (v[j] > bv) { bv = v[j]; bi = 4 * lane + j; }
        }
#pragma unroll
        for (int off = 32; off > 0; off >>= 1) {
            const float ov = __shfl_down(bv, off);
            const int   oi = __shfl_down(bi, off);
            if (ov > bv || (ov == bv && oi < bi)) { bv = ov; bi = oi; }
        }
        bi = __shfl(bi, 0);
        selIdx[it] = bi;
        if (lane == (bi >> 2)) v[bi & 3] = -INFINITY;
    }

    float wv[TOP_K];
    float wsum = 0.0f;
#pragma unroll
    for (int it = 0; it < TOP_K; it++) {
        wv[it] = sraw[selIdx[it]];
        wsum += wv[it];
    }
    const float inv = 2.5f / (wsum + 1e-20f);

#pragma unroll
    for (int it = 0; it < TOP_K; it++) {
        if (lane == it) {
            w_out[(size_t)t * TOP_K + it] = wv[it] * inv;
            i_out[(size_t)t * TOP_K + it] = (float)selIdx[it];
        }
    }
}

// ---------------------------------------------------------------------------
extern "C" void kernel_launch(void* const* d_in, const int* in_sizes, int n_in,
                              void* d_out, int out_size, void* d_ws, size_t ws_size,
                              hipStream_t stream) {
    const float* x    = (const float*)d_in[0];
    const float* w    = (const float*)d_in[1];
    const float* bias = (const float*)d_in[2];

    float* w_out = (float*)d_out;
    float* i_out = w_out + (size_t)T_DIM * TOP_K;

    const size_t PART = (size_t)T_DIM * E_DIM * sizeof(float); // 8.39 MB
    const size_t WT   = (size_t)E_DIM * D_DIM * sizeof(_Float16); // 3.67 MB

    int KS; bool convw;
    if      (ws_size >= 4 * PART + 2 * WT) { KS = 4; convw = false; }
    else if (ws_size >= 2 * PART + 2 * WT) { KS = 2; convw = false; }
    else if (ws_size >= 1 * PART + 2 * WT) { KS = 1; convw = false; }
    else                                   { KS = 1; convw = true;  }

    float* partial = (float*)d_ws;
    _Float16* wph = (_Float16*)((char*)d_ws + (size_t)KS * PART);
    _Float16* wpl = wph + (size_t)E_DIM * D_DIM;

    const int kslen = D_DIM / KS;

    if (!convw) {
        wprep_kernel<<<dim3(D_DIM / 64, E_DIM / 64), 256, 0, stream>>>(w, wph, wpl);
        gemm_split_kernel<false><<<dim3(KS, T_DIM / N_TOK), 512, 0, stream>>>(
            x, wph, wpl, w, partial, kslen);
    } else {
        gemm_split_kernel<true><<<dim3(KS, T_DIM / N_TOK), 512, 0, stream>>>(
            x, wph, wpl, w, partial, kslen);
    }
    router_kernel<<<T_DIM, 64, 0, stream>>>(partial, bias, w_out, i_out, KS);
}

// Round 4
// 379.282 us; speedup vs baseline: 1.0432x; 1.0432x over previous
//
#include <hip/hip_runtime.h>
#include <math.h>

#define T_DIM 8192
#define D_DIM 7168
#define E_DIM 256
#define N_GROUPS 8
#define TOPK_GROUPS 4
#define TOP_K 8

#define N_TOK 64      // tokens per GEMM block
#define BK 32         // k per chunk (one 16x16x32 MFMA k-step)
#define CHUNK_HALVES (E_DIM * BK)   // 8192 halves = 16 KB image per chunk per hi/lo
#define WSCALE 512.0f
#define INV_WSCALE (1.0f / 512.0f)

typedef _Float16 half8 __attribute__((ext_vector_type(8)));
typedef _Float16 half4v __attribute__((ext_vector_type(4)));
typedef float floatx4 __attribute__((ext_vector_type(4)));

#define WAITLGKM asm volatile("s_waitcnt lgkmcnt(0)" ::: "memory")
#define SCHEDB __builtin_amdgcn_sched_barrier(0)

// ---------------------------------------------------------------------------
// Kernel 0: split W [D][E] fp32 -> wph/wpl in per-lane FRAGMENT order:
// the half for (k = c*32 + g*8 + j, expert e) lives at halves-offset
//   ((c*4 + g)*256 + e)*8 + j
// so a GEMM lane (lm,kq) fetches its whole 8-half A-fragment for tile mt
// with ONE global_load_dwordx4 at base + c*16KB + (kq*256 + e)*16 B.
// 16 lanes read 256 contiguous bytes per granule row -> fully coalesced.
// A never touches LDS in the GEMM (zero intra-block reuse; L2/L3 serves the
// cross-block reuse).
// ---------------------------------------------------------------------------
__global__ __launch_bounds__(256) void wprep_kernel(
    const float* __restrict__ w, _Float16* __restrict__ wph, _Float16* __restrict__ wpl)
{
    __shared__ float tile[64][65];
    const int k0 = blockIdx.x * 64, e0 = blockIdx.y * 64;
    const int tid = threadIdx.x;
    {
        const int kk = tid >> 4, e4 = (tid & 15) * 4;
#pragma unroll
        for (int i = 0; i < 4; i++) {
            const float4 v = *(const float4*)(w + (size_t)(k0 + kk + i * 16) * E_DIM + e0 + e4);
            tile[kk + i * 16][e4 + 0] = v.x;
            tile[kk + i * 16][e4 + 1] = v.y;
            tile[kk + i * 16][e4 + 2] = v.z;
            tile[kk + i * 16][e4 + 3] = v.w;
        }
    }
    __syncthreads();
    {
        const int ee = tid >> 4, kk4 = (tid & 15) * 4;
        const int c_in = (k0 + kk4) >> 5;       // global chunk index
        const int g = (kk4 >> 3) & 3;           // granule within chunk
        const int j0 = kk4 & 7;                 // 0 or 4
#pragma unroll
        for (int i = 0; i < 4; i++) {
            const int el = ee + i * 16;
            const int e = e0 + el;
            half4v hh, ll;
#pragma unroll
            for (int j = 0; j < 4; j++) {
                const float v = tile[kk4 + j][el] * WSCALE;
                const _Float16 h = (_Float16)v;
                hh[j] = h;
                ll[j] = (_Float16)(v - (float)h);
            }
            const size_t off = ((size_t)(c_in * 4 + g) * E_DIM + e) * 8 + j0;
            *(half4v*)(wph + off) = hh;
            *(half4v*)(wpl + off) = ll;
        }
    }
}

// ---------------------------------------------------------------------------
// Kernel 1: split-fp16 MFMA GEMM, 256 threads (4 waves, disjoint 64-expert
// slices), 2 blocks/CU. A fragments: global->VGPR direct, double-buffered
// (named E/O register sets, statically unrolled x2 loop), prefetched one
// chunk ahead; compiler tracks each load's vmcnt. B (x tile): LDS,
// double-buffered, XOR-swizzled. One raw s_barrier + lgkmcnt(0) per chunk
// -- NO vmcnt drain, so A/x prefetch stays in flight across barriers.
// ---------------------------------------------------------------------------
__device__ __forceinline__ void cvt_split8(const float4 v0, const float4 v1,
                                           half8& h, half8& l)
{
    float f[8] = {v0.x, v0.y, v0.z, v0.w, v1.x, v1.y, v1.z, v1.w};
#pragma unroll
    for (int j = 0; j < 8; j++) {
        const _Float16 hh = (_Float16)f[j];
        h[j] = hh;
        l[j] = (_Float16)(f[j] - (float)hh);
    }
}

// load 4 hi + 4 lo A-fragments for chunk ci into named register buffers
#define LOAD_A(ci, AH, AL)                                                    \
    do {                                                                      \
        const char* ah_ = aHbase + (size_t)(ci) * (CHUNK_HALVES * 2);         \
        const char* al_ = aLbase + (size_t)(ci) * (CHUNK_HALVES * 2);         \
        _Pragma("unroll")                                                     \
        for (int mt_ = 0; mt_ < 4; mt_++) {                                   \
            AH[mt_] = *(const half8*)(ah_ + mt_ * 256);                       \
            AL[mt_] = *(const half8*)(al_ + mt_ * 256);                       \
        }                                                                     \
    } while (0)

// fallback: build A fragments from raw w[k][e] (bitwise-same split values)
#define LOAD_A_CONV(kc_, AH, AL)                                              \
    do {                                                                      \
        _Pragma("unroll")                                                     \
        for (int mt_ = 0; mt_ < 4; mt_++) {                                   \
            const int e_ = we0 + mt_ * 16 + lm;                               \
            _Pragma("unroll")                                                 \
            for (int jj_ = 0; jj_ < 8; jj_++) {                               \
                const float v_ =                                              \
                    wraw[(size_t)((kc_) + kq * 8 + jj_) * E_DIM + e_] * WSCALE; \
                const _Float16 h_ = (_Float16)v_;                             \
                AH[mt_][jj_] = h_;                                            \
                AL[mt_][jj_] = (_Float16)(v_ - (float)h_);                    \
            }                                                                 \
        }                                                                     \
    } while (0)

#define WRITE_B(buf, h_, l_)                                                  \
    do {                                                                      \
        const int boff_ = bt * BK + ((bg ^ ((bt >> 1) & 3)) << 3);            \
        *(half8*)&Bs[buf][0][boff_] = (h_);                                   \
        *(half8*)&Bs[buf][1][boff_] = (l_);                                   \
    } while (0)

#define COMPUTE_CHUNK(AH, AL, bb)                                             \
    do {                                                                      \
        __builtin_amdgcn_s_setprio(1);                                        \
        _Pragma("unroll")                                                     \
        for (int nt_ = 0; nt_ < 4; nt_++) {                                   \
            const int t_ = nt_ * 16 + lm;                                     \
            const int off_ = t_ * BK + ((kq ^ ((t_ >> 1) & 3)) << 3);         \
            const half8 bh = *(const half8*)&Bs[bb][0][off_];                 \
            const half8 bl = *(const half8*)&Bs[bb][1][off_];                 \
            _Pragma("unroll")                                                 \
            for (int mt_ = 0; mt_ < 4; mt_++) {                               \
                acc[mt_][nt_] = __builtin_amdgcn_mfma_f32_16x16x32_f16(AH[mt_], bh, acc[mt_][nt_], 0, 0, 0); \
                acc[mt_][nt_] = __builtin_amdgcn_mfma_f32_16x16x32_f16(AH[mt_], bl, acc[mt_][nt_], 0, 0, 0); \
                acc[mt_][nt_] = __builtin_amdgcn_mfma_f32_16x16x32_f16(AL[mt_], bh, acc[mt_][nt_], 0, 0, 0); \
            }                                                                 \
        }                                                                     \
        __builtin_amdgcn_s_setprio(0);                                        \
    } while (0)

#define BARRIER_PUB                                                            \
    do { WAITLGKM; SCHEDB; __builtin_amdgcn_s_barrier(); SCHEDB; } while (0)

// chunk body: prefetch chunk i+1 (A->regs, x->regs), compute chunk i,
// then cvt+write B(i+1) and publish. pc/pn are compile-time 0/1.
#define CHUNK_BODY(i_, AHc, ALc, AHn, ALn, pc, pn)                            \
    do {                                                                      \
        const int kc_ = k0 + (i_) * BK;                                       \
        const float4 xn0 = *(const float4*)(xrow + kc_ + BK);                 \
        const float4 xn1 = *(const float4*)(xrow + kc_ + BK + 4);             \
        if constexpr (CONVW) { LOAD_A_CONV(kc_ + BK, AHn, ALn); }             \
        else                 { LOAD_A(cbase + (i_) + 1, AHn, ALn); }          \
        COMPUTE_CHUNK(AHc, ALc, pc);                                          \
        {                                                                     \
            half8 h_, l_;                                                     \
            cvt_split8(xn0, xn1, h_, l_);                                     \
            WRITE_B(pn, h_, l_);                                              \
        }                                                                     \
        BARRIER_PUB;                                                          \
    } while (0)

template <bool CONVW>
__global__ __launch_bounds__(256, 2) void gemm_split_kernel(
    const float* __restrict__ x, const _Float16* __restrict__ wph,
    const _Float16* __restrict__ wpl, const float* __restrict__ wraw,
    float* __restrict__ partial, int kslen)
{
    __shared__ _Float16 Bs[2][2][N_TOK * BK]; // [parity][hi/lo] = 16 KB

    const int s = blockIdx.x, m = blockIdx.y;
    const int tid = threadIdx.x;
    const int k0 = s * kslen;
    const size_t t0 = (size_t)m * N_TOK;

    const int wave = tid >> 6, lane = tid & 63;
    const int lm = lane & 15, kq = lane >> 4; // fragment row / k-granule
    const int we0 = wave * 64;                // wave's expert base (4 waves x 64e)

    // B staging map: thread -> (token, k-granule)
    const int bt = tid >> 2;   // 0..63
    const int bg = tid & 3;    // 0..3
    const float* xrow = x + (t0 + bt) * (size_t)D_DIM + bg * 8;

    // per-lane A fragment base pointers (chunk-image fragment order)
    const int cbase = k0 / BK;
    const int laneAoff = (kq * E_DIM + we0 + lm) * 16; // bytes within chunk image
    const char* aHbase = (const char*)wph + laneAoff;
    const char* aLbase = (const char*)wpl + laneAoff;

    floatx4 acc[4][4];
#pragma unroll
    for (int mt = 0; mt < 4; mt++)
#pragma unroll
        for (int nt = 0; nt < 4; nt++) acc[mt][nt] = (floatx4)0.0f;

    const int nch = kslen / BK;   // 56 at KS=4 (always even)

    half8 aHE[4], aLE[4], aHO[4], aLO[4];

    // ---- prologue: A(0)->E regs, x(0)->B[0] ----
    {
        const float4 x0a = *(const float4*)(xrow + k0);
        const float4 x0b = *(const float4*)(xrow + k0 + 4);
        if constexpr (CONVW) { LOAD_A_CONV(k0, aHE, aLE); }
        else                 { LOAD_A(cbase, aHE, aLE); }
        half8 h, l;
        cvt_split8(x0a, x0b, h, l);
        WRITE_B(0, h, l);
        BARRIER_PUB;
    }

    // ---- main loop: statically unrolled x2 (named E/O buffers) ----
    for (int i = 0; i < nch - 2; i += 2) {
        CHUNK_BODY(i,     aHE, aLE, aHO, aLO, 0, 1);
        CHUNK_BODY(i + 1, aHO, aLO, aHE, aLE, 1, 0);
    }
    // chunk nch-2 (even parity), prefetches nch-1
    CHUNK_BODY(nch - 2, aHE, aLE, aHO, aLO, 0, 1);
    // chunk nch-1 (odd parity), compute only
    COMPUTE_CHUNK(aHO, aLO, 1);

    // ---- epilogue: store raw z' partials. C/D: col(token)=lane&15, row(e)=(lane>>4)*4+r
    float* pout = partial + (size_t)s * T_DIM * E_DIM;
    const int rq = lane >> 4;
#pragma unroll
    for (int nt = 0; nt < 4; nt++) {
        const size_t t = t0 + nt * 16 + lm;
#pragma unroll
        for (int mt = 0; mt < 4; mt++) {
            const int e = we0 + mt * 16 + rq * 4;
            *(floatx4*)(pout + t * E_DIM + e) = acc[mt][nt];
        }
    }
}

// ---------------------------------------------------------------------------
// Kernel 2: per-token routing. One wave per token, no barriers.
// Sums KS partials, z = sum * (1/512), score = sigmoid(z).
// ---------------------------------------------------------------------------
__global__ __launch_bounds__(64) void router_kernel(
    const float* __restrict__ partial, const float* __restrict__ bias,
    float* __restrict__ w_out, float* __restrict__ i_out, int ks)
{
    const int t = blockIdx.x;
    const int lane = threadIdx.x;

    __shared__ float sraw[E_DIM];

    float4 zv = make_float4(0.f, 0.f, 0.f, 0.f);
    for (int s = 0; s < ks; s++) {
        const float4 p = *(const float4*)(partial + (size_t)s * T_DIM * E_DIM +
                                          (size_t)t * E_DIM + lane * 4);
        zv.x += p.x; zv.y += p.y; zv.z += p.z; zv.w += p.w;
    }
    float4 sv;
    sv.x = 1.0f / (1.0f + expf(-zv.x * INV_WSCALE));
    sv.y = 1.0f / (1.0f + expf(-zv.y * INV_WSCALE));
    sv.z = 1.0f / (1.0f + expf(-zv.z * INV_WSCALE));
    sv.w = 1.0f / (1.0f + expf(-zv.w * INV_WSCALE));

    const float4 bz = *(const float4*)(bias + lane * 4);
    *(float4*)(&sraw[lane * 4]) = sv; // single wave: no barrier needed

    float sb[4];
    sb[0] = sv.x + bz.x; sb[1] = sv.y + bz.y; sb[2] = sv.z + bz.z; sb[3] = sv.w + bz.w;

    // group top-2 sum (8 lanes per group)
    float m1 = -INFINITY, m2 = -INFINITY;
#pragma unroll
    for (int j = 0; j < 4; j++) {
        const float v = sb[j];
        if (v > m1) { m2 = m1; m1 = v; }
        else if (v > m2) { m2 = v; }
    }
#pragma unroll
    for (int d = 1; d < 8; d <<= 1) {
        const float o1 = __shfl_xor(m1, d);
        const float o2 = __shfl_xor(m2, d);
        const float hi = fmaxf(m1, o1);
        const float lo = fminf(m1, o1);
        m2 = fmaxf(lo, fmaxf(m2, o2));
        m1 = hi;
    }
    const float gscore = m1 + m2;

    float gs[N_GROUPS];
#pragma unroll
    for (int g = 0; g < N_GROUPS; g++) gs[g] = __shfl(gscore, g * 8);

    unsigned gmask = 0u;
#pragma unroll
    for (int r = 0; r < TOPK_GROUPS; r++) {
        int best = 0; float bv = -INFINITY;
#pragma unroll
        for (int g = 0; g < N_GROUPS; g++) {
            const bool taken = (gmask >> g) & 1u;
            if (!taken && gs[g] > bv) { bv = gs[g]; best = g; }
        }
        gmask |= (1u << best);
    }

    const int myg = lane >> 3;
    const float keep = ((gmask >> myg) & 1u) ? 1.0f : 0.0f;
    float v[4];
#pragma unroll
    for (int j = 0; j < 4; j++) v[j] = keep * sb[j];

    int selIdx[TOP_K];
#pragma unroll
    for (int it = 0; it < TOP_K; it++) {
        float bv = -INFINITY; int bi = E_DIM;
#pragma unroll
        for (int j = 0; j < 4; j++) {
            if (v[j] > bv) { bv = v[j]; bi = 4 * lane + j; }
        }
#pragma unroll
        for (int off = 32; off > 0; off >>= 1) {
            const float ov = __shfl_down(bv, off);
            const int   oi = __shfl_down(bi, off);
            if (ov > bv || (ov == bv && oi < bi)) { bv = ov; bi = oi; }
        }
        bi = __shfl(bi, 0);
        selIdx[it] = bi;
        if (lane == (bi >> 2)) v[bi & 3] = -INFINITY;
    }

    float wv[TOP_K];
    float wsum = 0.0f;
#pragma unroll
    for (int it = 0; it < TOP_K; it++) {
        wv[it] = sraw[selIdx[it]];
        wsum += wv[it];
    }
    const float inv = 2.5f / (wsum + 1e-20f);

#pragma unroll
    for (int it = 0; it < TOP_K; it++) {
        if (lane == it) {
            w_out[(size_t)t * TOP_K + it] = wv[it] * inv;
            i_out[(size_t)t * TOP_K + it] = (float)selIdx[it];
        }
    }
}

// ---------------------------------------------------------------------------
extern "C" void kernel_launch(void* const* d_in, const int* in_sizes, int n_in,
                              void* d_out, int out_size, void* d_ws, size_t ws_size,
                              hipStream_t stream) {
    const float* x    = (const float*)d_in[0];
    const float* w    = (const float*)d_in[1];
    const float* bias = (const float*)d_in[2];

    float* w_out = (float*)d_out;
    float* i_out = w_out + (size_t)T_DIM * TOP_K;

    const size_t PART = (size_t)T_DIM * E_DIM * sizeof(float); // 8.39 MB
    const size_t WT   = (size_t)E_DIM * D_DIM * sizeof(_Float16); // 3.67 MB

    int KS; bool convw;
    if      (ws_size >= 4 * PART + 2 * WT) { KS = 4; convw = false; }
    else if (ws_size >= 2 * PART + 2 * WT) { KS = 2; convw = false; }
    else if (ws_size >= 1 * PART + 2 * WT) { KS = 1; convw = false; }
    else                                   { KS = 1; convw = true;  }

    float* partial = (float*)d_ws;
    _Float16* wph = (_Float16*)((char*)d_ws + (size_t)KS * PART);
    _Float16* wpl = wph + (size_t)E_DIM * D_DIM;

    const int kslen = D_DIM / KS;

    if (!convw) {
        wprep_kernel<<<dim3(D_DIM / 64, E_DIM / 64), 256, 0, stream>>>(w, wph, wpl);
        gemm_split_kernel<false><<<dim3(KS, T_DIM / N_TOK), 256, 0, stream>>>(
            x, wph, wpl, w, partial, kslen);
    } else {
        gemm_split_kernel<true><<<dim3(KS, T_DIM / N_TOK), 256, 0, stream>>>(
            x, wph, wpl, w, partial, kslen);
    }
    router_kernel<<<T_DIM, 64, 0, stream>>>(partial, bias, w_out, i_out, KS);
}